// Round 13
// baseline (31.842 us; speedup 1.0000x reference)
//
#include <hip/hip_runtime.h>
#include <math.h>

// Problem constants (verified against setup_inputs): E=1024, CTX=1024.
#define EDIM 1024
#define CTXDIM 1024
#define H2 2048
#define NH 512            // h-producer blocks (2 cols each)
#define NMS 256           // mu/sigma blocks (8 rows each)

// ws float layout:
//   [0    : 2048)  h        (written via relaxed agent-atomic stores)
//   [2048 : 3072)  mu
//   [3072 : 4096)  sigma
//   [4096 : 6240)  barrier state: 67 x 128B lines (memset to 0 each launch):
//                  0-15 leaf0, 16 root0, 17-32 done0,
//                  33-48 leaf1, 49 root1, 50-65 done1, 66 finale
//   [6272 : 6824)  Sbuf: [0]=logdet, [1]=S_x, [2..52)=pos, [52..552)=neg

#define AST(p, v) __hip_atomic_store((p), (v), __ATOMIC_RELAXED, __HIP_MEMORY_SCOPE_AGENT)
#define ALD(p)    __hip_atomic_load((p), __ATOMIC_RELAXED, __HIP_MEMORY_SCOPE_AGENT)

// Single kernel, 837 blocks x 512 thr, three roles (producer-consumer chain,
// all blocks co-resident: 6696 waves <= 8192, 27KB LDS/CU, 4 blk/CU cap).
// Cross-block data via relaxed agent atomics (proven r6/r10/r12, absmax 0.0).
__global__ __launch_bounds__(512) void k_all(
    const float* __restrict__ emb, const float* __restrict__ Mw,
    const float* __restrict__ Mb, const float* __restrict__ Uw,
    const float* __restrict__ Ub, const float* __restrict__ Ww,
    const float* __restrict__ Wb, const float* __restrict__ pmu,
    const float* __restrict__ psig, const int* __restrict__ x,
    const int* __restrict__ ctx, const int* __restrict__ negs,
    int C, int CN, int NEG, int KDIM, int nsblk,
    float* __restrict__ ws, float* __restrict__ out)
{
    __shared__ float smem[2048];     // h-prod: unused; musig: h; S: mu|sigma
    __shared__ int   idxs[64];
    __shared__ float pacc[8];
    __shared__ float pxs[2];
    const int tid  = threadIdx.x;
    const int w    = tid >> 6;
    const int lane = tid & 63;
    const int b    = blockIdx.x;
    unsigned* bar  = (unsigned*)(ws + 4096);
    float* Sbuf    = ws + 6272;

    if (b < NH) {
        // ---------------- role 1: h producer (cols 2b, 2b+1) ----------------
        if (tid <= C) idxs[tid] = (tid == 0) ? x[0] : ctx[tid - 1];
        const int c = w & 1;                 // local col
        const int g = w >> 1;                // row group (0..3)
        const int j = b * 2 + c;
        const float4* mrow = (const float4*)(Mw + (size_t)j * EDIM);
        const float4 mw0 = mrow[lane];
        const float4 mw1 = mrow[lane + 64];
        const float4 mw2 = mrow[lane + 128];
        const float4 mw3 = mrow[lane + 192];
        const float bj = Mb[j];
        __syncthreads();

        float acc = 0.f, px = 0.f;
#pragma unroll 2
        for (int r = g; r <= C; r += 4) {
            const int idx = idxs[r];
            const float4* e4 = (const float4*)(emb + (size_t)idx * EDIM);
            const float4 a  = e4[lane];
            const float4 bb = e4[lane + 64];
            const float4 d  = e4[lane + 128];
            const float4 e  = e4[lane + 192];
            float s = a.x*mw0.x + a.y*mw0.y + a.z*mw0.z + a.w*mw0.w;
            s += bb.x*mw1.x + bb.y*mw1.y + bb.z*mw1.z + bb.w*mw1.w;
            s += d.x*mw2.x + d.y*mw2.y + d.z*mw2.z + d.w*mw2.w;
            s += e.x*mw3.x + e.y*mw3.y + e.z*mw3.z + e.w*mw3.w;
#pragma unroll
            for (int m = 32; m >= 1; m >>= 1) s += __shfl_xor(s, m);
            const float v = fmaxf(s + bj, 0.f);
            if (r == 0) px = (float)C * v;   // x-row appears only in group 0
            else        acc += v;
        }
        if (lane == 0) {
            pacc[w] = acc;
            if (g == 0) pxs[c] = px;
        }
        __syncthreads();
        if (tid < 2) {
            const int jj = b * 2 + tid;
            AST(&ws[jj], pxs[tid]);
            AST(&ws[CTXDIM + jj],
                pacc[tid] + pacc[tid + 2] + pacc[tid + 4] + pacc[tid + 6]);
        }
        __syncthreads();                     // stores acked at coherence point
        if (tid == 0) {                      // tree0 arrival (512/16 = 32/leaf)
            const unsigned old = __hip_atomic_fetch_add(&bar[32 * (b & 15)], 1u,
                                   __ATOMIC_RELAXED, __HIP_MEMORY_SCOPE_AGENT);
            if (old == 31u) {
                const unsigned o2 = __hip_atomic_fetch_add(&bar[32 * 16], 1u,
                                      __ATOMIC_RELAXED, __HIP_MEMORY_SCOPE_AGENT);
                if (o2 == 15u) {
#pragma unroll
                    for (int i = 0; i < 16; ++i) AST(&bar[32 * (17 + i)], 1u);
                }
            }
        }
        return;
    }

    if (b < NH + NMS) {
        // ---------------- role 2: mu/sigma (8 rows/block) ----------------
        const int mb = b - NH;
        const int W = mb * 8 + w;            // 0..2047
        const bool is_mu = (W < CTXDIM);
        const int rr = W & (CTXDIM - 1);
        const float4* Wr4 = (const float4*)((is_mu ? Uw : Ww) + (size_t)rr * H2);

        // Preload weights + bias into registers BEFORE the spin.
        float4 wv[8];
#pragma unroll
        for (int k = 0; k < 8; ++k) wv[k] = Wr4[lane + 64 * k];
        const float bias = is_mu ? Ub[rr] : Wb[rr];

        if (tid == 0) {                      // spin until h is done
            while (ALD(&bar[32 * (17 + (mb & 15))]) == 0u)
                __builtin_amdgcn_s_sleep(8);
        }
        __syncthreads();
        __builtin_amdgcn_sched_barrier(0);   // no hoisting above the spin

        {   // stage h via 8B coherent loads (2 per thread)
            const unsigned long long* src = (const unsigned long long*)ws;
#pragma unroll
            for (int q = 0; q < 2; ++q) {
                const int i = tid + 512 * q;
                const unsigned long long v = __hip_atomic_load(&src[i],
                    __ATOMIC_RELAXED, __HIP_MEMORY_SCOPE_AGENT);
                smem[2 * i]     = __uint_as_float((unsigned)(v & 0xffffffffu));
                smem[2 * i + 1] = __uint_as_float((unsigned)(v >> 32));
            }
        }
        __syncthreads();

        const float4* h4 = (const float4*)smem;
        float s = 0.f;
#pragma unroll
        for (int k = 0; k < 8; ++k) {
            const float4 hv = h4[lane + 64 * k];
            s += wv[k].x*hv.x + wv[k].y*hv.y + wv[k].z*hv.z + wv[k].w*hv.w;
        }
#pragma unroll
        for (int m = 32; m >= 1; m >>= 1) s += __shfl_xor(s, m);
        if (lane == 0) {
            if (is_mu) {
                AST(&ws[2048 + rr], s + bias);
            } else {
                const float v = s + bias;
                AST(&ws[3072 + rr], fmaxf(v, 0.f) + log1pf(expf(-fabsf(v))));
            }
        }
        __syncthreads();                     // stores acked
        if (tid == 0) {                      // tree1 arrival (256/16 = 16/leaf)
            const unsigned old = __hip_atomic_fetch_add(&bar[32 * (33 + (mb & 15))], 1u,
                                   __ATOMIC_RELAXED, __HIP_MEMORY_SCOPE_AGENT);
            if (old == 15u) {
                const unsigned o2 = __hip_atomic_fetch_add(&bar[32 * 49], 1u,
                                      __ATOMIC_RELAXED, __HIP_MEMORY_SCOPE_AGENT);
                if (o2 == 15u) {
#pragma unroll
                    for (int i = 0; i < 16; ++i) AST(&bar[32 * (50 + i)], 1u);
                }
            }
        }
        return;
    }

    // ---------------- role 3: S consumer + finale ----------------
    const int sc = b - NH - NMS;             // 0..nsblk-1
    const int t = sc * 8 + w;                // 0..551
    const int ntask = 2 + C + CN;            // 552

    // 1) Prior gathers into registers before the spin.
    const bool iskl = (t >= 1 && t < ntask);
    float4 gm[4], gsv[4];
    if (iskl) {
        int idx;
        if (t == 1)          idx = x[0];
        else if (t < 2 + C)  idx = ctx[t - 2];
        else                 idx = negs[t - 2 - C];
        const float4* m4 = (const float4*)(pmu  + (size_t)idx * CTXDIM);
        const float4* s4 = (const float4*)(psig + (size_t)idx * CTXDIM);
#pragma unroll
        for (int k = 0; k < 4; ++k) {
            gm[k]  = m4[lane + 64 * k];
            gsv[k] = s4[lane + 64 * k];
        }
    }

    // 2) Spin until mu/sigma done (gathers complete meanwhile).
    if (tid == 0) {
        while (ALD(&bar[32 * (50 + (sc & 15))]) == 0u)
            __builtin_amdgcn_s_sleep(8);
    }
    __syncthreads();
    __builtin_amdgcn_sched_barrier(0);

    // 3) Stage mu/sigma via 8B coherent loads.
    {
        const unsigned long long* src = (const unsigned long long*)(ws + 2048);
#pragma unroll
        for (int q = 0; q < 2; ++q) {
            const int i = tid + 512 * q;
            const unsigned long long v = __hip_atomic_load(&src[i],
                __ATOMIC_RELAXED, __HIP_MEMORY_SCOPE_AGENT);
            smem[2 * i]     = __uint_as_float((unsigned)(v & 0xffffffffu));
            smem[2 * i + 1] = __uint_as_float((unsigned)(v >> 32));
        }
    }
    __syncthreads();

    // 4) Compute S(t).
    {
        float acc = 0.f;
        if (t == 0) {                        // logdet = sum log sigma
#pragma unroll
            for (int k = 0; k < 16; ++k) acc += logf(smem[1024 + lane + 64 * k]);
        } else {
            const float4* ms4 = (const float4*)smem;
#pragma unroll
            for (int k = 0; k < 4; ++k) {
                const int i = lane + 64 * k;
                const float4 m  = gm[k];
                const float4 sv = gsv[k];
                const float4 mu = ms4[i];
                const float4 sg = ms4[256 + i];
                { const float s2 = sv.x*sv.x; const float dd = m.x-mu.x; acc += (sg.x + dd*dd)/s2 + logf(s2); }
                { const float s2 = sv.y*sv.y; const float dd = m.y-mu.y; acc += (sg.y + dd*dd)/s2 + logf(s2); }
                { const float s2 = sv.z*sv.z; const float dd = m.z-mu.z; acc += (sg.z + dd*dd)/s2 + logf(s2); }
                { const float s2 = sv.w*sv.w; const float dd = m.w-mu.w; acc += (sg.w + dd*dd)/s2 + logf(s2); }
            }
        }
#pragma unroll
        for (int m = 32; m >= 1; m >>= 1) acc += __shfl_xor(acc, m);
        if (lane == 0) AST(&Sbuf[t], acc);
    }

    __syncthreads();                         // block's S stores drained
    if (w == 0) {                            // wave-uniform finale protocol
        __builtin_amdgcn_fence(__ATOMIC_RELEASE, "agent");   // one wb per block
        int win = 0;
        if (lane == 0) {
            const unsigned old = __hip_atomic_fetch_add(&bar[32 * 66], 1u,
                                   __ATOMIC_RELAXED, __HIP_MEMORY_SCOPE_AGENT);
            win = (old == (unsigned)(nsblk - 1));
        }
        win = __shfl(win, 0);
        if (win) {
            __builtin_amdgcn_fence(__ATOMIC_ACQUIRE, "agent");
            float lik = 0.f;
            for (int i = lane; i < CN; i += 64) {
                const float sn = ALD(&Sbuf[2 + C + i]);
                const float sp = ALD(&Sbuf[2 + i / NEG]);
                lik += fmaxf(0.f, 0.5f * (sn - sp) + 1.0f);   // kl_neg - kl_pos + 1
            }
#pragma unroll
            for (int m = 32; m >= 1; m >>= 1) lik += __shfl_xor(lik, m);
            if (lane == 0) {
                const float ld = ALD(&Sbuf[0]);
                const float sx = ALD(&Sbuf[1]);
                out[0] = lik - 0.5f * (sx - (float)KDIM - ld);  // - kl_prior
            }
        }
    }
}

extern "C" void kernel_launch(void* const* d_in, const int* in_sizes, int n_in,
                              void* d_out, int out_size, void* d_ws, size_t ws_size,
                              hipStream_t stream) {
    const int*   x    = (const int*)d_in[0];
    const int*   ctx  = (const int*)d_in[1];
    const int*   negs = (const int*)d_in[2];
    const float* emb  = (const float*)d_in[3];
    const float* Mw   = (const float*)d_in[4];
    const float* Mb   = (const float*)d_in[5];
    const float* Uw   = (const float*)d_in[6];
    const float* Ub   = (const float*)d_in[7];
    const float* Ww   = (const float*)d_in[8];
    const float* Wb   = (const float*)d_in[9];
    const float* pmu  = (const float*)d_in[10];
    const float* psig = (const float*)d_in[11];
    float* ws  = (float*)d_ws;
    float* out = (float*)d_out;

    const int C    = in_sizes[1];          // 50
    const int CN   = in_sizes[2];          // 500
    const int NEG  = CN / C;               // 10
    const int KDIM = in_sizes[5];          // CTX = 1024

    const int ntask = 2 + C + CN;          // 552
    const int nsblk = (ntask + 7) / 8;     // 69 consumer blocks

    // Zero the 67-line barrier state (graph-legal async memset node).
    (void)hipMemsetAsync((char*)d_ws + 4096 * sizeof(float), 0, 67 * 128, stream);
    k_all<<<NH + NMS + nsblk, 512, 0, stream>>>(emb, Mw, Mb, Uw, Ub, Ww, Wb,
                                                pmu, psig, x, ctx, negs,
                                                C, CN, NEG, KDIM, nsblk, ws, out);
}

// Round 14
// 27.202 us; speedup vs baseline: 1.1706x; 1.1706x over previous
//
#include <hip/hip_runtime.h>
#include <math.h>

// Problem constants (verified against setup_inputs): E=1024, CTX=1024.
#define EDIM 1024
#define CTXDIM 1024
#define H2 2048

// ws float layout:
//   [0    : 2048)  h
//   [2048 : 3072)  mu      (K2: written via relaxed agent-atomic stores)
//   [3072 : 4096)  sigma
//   [4096 : 5184)  barrier state: 34 x 128B lines (zeroed by k_h block 0):
//                  line i<16: leaf[i]; line 16: root; 17..32: done[i]; 33: finale
//   [5248 : 5800)  Sbuf: [0]=logdet, [1]=S_x, [2..52)=pos, [52..552)=neg

#define AST(p, v) __hip_atomic_store((p), (v), __ATOMIC_RELAXED, __HIP_MEMORY_SCOPE_AGENT)
#define ALD(p)    __hip_atomic_load((p), __ATOMIC_RELAXED, __HIP_MEMORY_SCOPE_AGENT)

// ---------------- Kernel 1: h[2048] ----------------
// 256 blocks x 1024 thr (16 waves). Block owns 4 cols; wave (c,g) = col 4b+c,
// rows r ≡ g (mod 4) of the 1+C input rows (row 0 = x). Block 0 zeroes the
// K2 barrier state (stream order + kernel-boundary flush make it visible).
__global__ __launch_bounds__(1024) void k_h(
    const float* __restrict__ emb, const float* __restrict__ Mw,
    const float* __restrict__ Mb, const int* __restrict__ x,
    const int* __restrict__ ctx, int C, float* __restrict__ ws)
{
    __shared__ int   idxs[64];
    __shared__ float pacc[16];
    __shared__ float pxs[4];
    const int tid  = threadIdx.x;
    const int w    = tid >> 6;
    const int lane = tid & 63;
    const int c    = w & 3;
    const int g    = w >> 2;
    const int j    = blockIdx.x * 4 + c;

    if (blockIdx.x == 0) {
        ws[4096 + tid] = 0.f;                  // 1024 of the 1088 counter words
        if (tid < 64) ws[5120 + tid] = 0.f;    // remainder
    }
    if (tid <= C) idxs[tid] = (tid == 0) ? x[0] : ctx[tid - 1];

    const float4* mrow = (const float4*)(Mw + (size_t)j * EDIM);
    const float4 mw0 = mrow[lane];
    const float4 mw1 = mrow[lane + 64];
    const float4 mw2 = mrow[lane + 128];
    const float4 mw3 = mrow[lane + 192];
    const float bj = Mb[j];
    __syncthreads();

    float acc = 0.f, px = 0.f;
#pragma unroll 2
    for (int r = g; r <= C; r += 4) {
        const int idx = idxs[r];
        const float4* e4 = (const float4*)(emb + (size_t)idx * EDIM);
        const float4 a  = e4[lane];
        const float4 bb = e4[lane + 64];
        const float4 d  = e4[lane + 128];
        const float4 e  = e4[lane + 192];
        float s = a.x*mw0.x + a.y*mw0.y + a.z*mw0.z + a.w*mw0.w;
        s += bb.x*mw1.x + bb.y*mw1.y + bb.z*mw1.z + bb.w*mw1.w;
        s += d.x*mw2.x + d.y*mw2.y + d.z*mw2.z + d.w*mw2.w;
        s += e.x*mw3.x + e.y*mw3.y + e.z*mw3.z + e.w*mw3.w;
#pragma unroll
        for (int m = 32; m >= 1; m >>= 1) s += __shfl_xor(s, m);
        const float v = fmaxf(s + bj, 0.f);
        if (r == 0) px = (float)C * v;   // x-row appears only in group 0
        else        acc += v;
    }
    if (lane == 0) {
        pacc[w] = acc;
        if (g == 0) pxs[c] = px;
    }
    __syncthreads();
    if (tid < 4) {
        const int jj = blockIdx.x * 4 + tid;
        ws[jj]          = pxs[tid];
        ws[CTXDIM + jj] = pacc[tid] + pacc[tid + 4] + pacc[tid + 8] + pacc[tid + 12];
    }
}

// ---------------- Kernel 2: producer-consumer tail ----------------
// 325 blocks x 512 thr.
//   Blocks 0..255 (producers): 8 mu/sigma rows/block, one wave per row, full
//     2048-dot; results stored via relaxed agent atomics; tree arrival
//     (16 leaves -> root -> 16 done flags).
//   Blocks 256..324 (consumers): 8 S-tasks/block (t = (b-256)*8 + w; 552 total).
//     Prior gathers issued into registers BEFORE the spin (latency hidden).
//     Spin on sharded done flag, stage mu/sigma via 8B atomic loads, compute,
//     store S via atomic store; last-arriving consumer computes hinge + out.
__global__ __launch_bounds__(512) void k_tail(
    const float* __restrict__ Uw, const float* __restrict__ Ub,
    const float* __restrict__ Ww, const float* __restrict__ Wb,
    const float* __restrict__ pmu, const float* __restrict__ psig,
    const int* __restrict__ x, const int* __restrict__ ctx,
    const int* __restrict__ negs, int C, int CN, int NEG, int KDIM,
    int nsblk, float* __restrict__ ws, float* __restrict__ out)
{
    __shared__ float smem[2048];               // producers: h; consumers: mu|sigma
    __shared__ int   winflag;
    const int tid  = threadIdx.x;
    const int w    = tid >> 6;
    const int lane = tid & 63;
    const int b    = blockIdx.x;
    unsigned* bar  = (unsigned*)(ws + 4096);
    float* Sbuf    = ws + 5248;

    if (b < 256) {
        // ---------------- producer: mu, sigma ----------------
        float4* hbuf = (float4*)smem;
        hbuf[tid] = ((const float4*)ws)[tid];  // h from k_h (kernel boundary)
        __syncthreads();

        const int W = b * 8 + w;               // 0..2047
        const bool is_mu = (W < CTXDIM);
        const int rr = W & (CTXDIM - 1);
        const float4* Wr4 = (const float4*)((is_mu ? Uw : Ww) + (size_t)rr * H2);
        float s = 0.f;
#pragma unroll
        for (int k = 0; k < 8; ++k) {
            const float4 wv = Wr4[lane + 64 * k];
            const float4 hv = hbuf[lane + 64 * k];
            s += wv.x*hv.x + wv.y*hv.y + wv.z*hv.z + wv.w*hv.w;
        }
#pragma unroll
        for (int m = 32; m >= 1; m >>= 1) s += __shfl_xor(s, m);
        if (lane == 0) {
            if (is_mu) {
                AST(&ws[2048 + rr], s + Ub[rr]);
            } else {
                const float v = s + Wb[rr];
                AST(&ws[3072 + rr], fmaxf(v, 0.f) + log1pf(expf(-fabsf(v))));
            }
        }
        __syncthreads();                       // block's stores acked at CP
        if (tid == 0) {
            const unsigned old = __hip_atomic_fetch_add(&bar[32 * (b & 15)], 1u,
                                   __ATOMIC_RELAXED, __HIP_MEMORY_SCOPE_AGENT);
            if (old == 15u) {                  // leaf full
                const unsigned o2 = __hip_atomic_fetch_add(&bar[32 * 16], 1u,
                                      __ATOMIC_RELAXED, __HIP_MEMORY_SCOPE_AGENT);
                if (o2 == 15u) {               // all leaves: broadcast done
#pragma unroll
                    for (int i = 0; i < 16; ++i)
                        AST(&bar[32 * (17 + i)], 1u);
                }
            }
        }
        return;
    }

    // ---------------- consumer: S tasks + finale ----------------
    const int t = (b - 256) * 8 + w;           // 0..551
    const int ntask = 2 + C + CN;              // 552

    // 1) Issue prior gathers into registers before the spin.
    const bool iskl = (t >= 1 && t < ntask);
    float4 gm[4], gsv[4];
    if (iskl) {
        int idx;
        if (t == 1)          idx = x[0];
        else if (t < 2 + C)  idx = ctx[t - 2];
        else                 idx = negs[t - 2 - C];
        const float4* m4 = (const float4*)(pmu  + (size_t)idx * CTXDIM);
        const float4* s4 = (const float4*)(psig + (size_t)idx * CTXDIM);
#pragma unroll
        for (int k = 0; k < 4; ++k) {
            gm[k]  = m4[lane + 64 * k];
            gsv[k] = s4[lane + 64 * k];
        }
    }

    // 2) Spin until producers done (sharded flag; gathers complete meanwhile).
    if (tid == 0) {
        while (ALD(&bar[32 * (17 + (b & 15))]) == 0u)
            __builtin_amdgcn_s_sleep(8);
    }
    __syncthreads();
    __builtin_amdgcn_sched_barrier(0);         // no hoisting above the spin

    // 3) Stage mu/sigma via 8B coherent loads (2 per thread).
    {
        const unsigned long long* src = (const unsigned long long*)(ws + 2048);
#pragma unroll
        for (int q = 0; q < 2; ++q) {
            const int i = tid + 512 * q;
            const unsigned long long v = __hip_atomic_load(&src[i],
                __ATOMIC_RELAXED, __HIP_MEMORY_SCOPE_AGENT);
            smem[2 * i]     = __uint_as_float((unsigned)(v & 0xffffffffu));
            smem[2 * i + 1] = __uint_as_float((unsigned)(v >> 32));
        }
    }
    __syncthreads();

    // 4) Compute S(t).
    {
        float acc = 0.f;
        if (t == 0) {                          // logdet = sum log sigma
#pragma unroll
            for (int k = 0; k < 16; ++k) acc += logf(smem[1024 + lane + 64 * k]);
        } else {
            const float4* ms4 = (const float4*)smem;
#pragma unroll
            for (int k = 0; k < 4; ++k) {
                const int i = lane + 64 * k;
                const float4 m  = gm[k];
                const float4 sv = gsv[k];
                const float4 mu = ms4[i];
                const float4 sg = ms4[256 + i];
                { const float s2 = sv.x*sv.x; const float dd = m.x-mu.x; acc += (sg.x + dd*dd)/s2 + logf(s2); }
                { const float s2 = sv.y*sv.y; const float dd = m.y-mu.y; acc += (sg.y + dd*dd)/s2 + logf(s2); }
                { const float s2 = sv.z*sv.z; const float dd = m.z-mu.z; acc += (sg.z + dd*dd)/s2 + logf(s2); }
                { const float s2 = sv.w*sv.w; const float dd = m.w-mu.w; acc += (sg.w + dd*dd)/s2 + logf(s2); }
            }
        }
#pragma unroll
        for (int m = 32; m >= 1; m >>= 1) acc += __shfl_xor(acc, m);
        if (lane == 0) AST(&Sbuf[t], acc);
    }

    __syncthreads();                           // block's S stores drained
    if (w == 0) {                              // wave-uniform finale protocol
        __builtin_amdgcn_fence(__ATOMIC_RELEASE, "agent");   // one wb per block
        int win = 0;
        if (lane == 0) {
            const unsigned old = __hip_atomic_fetch_add(&bar[32 * 33], 1u,
                                   __ATOMIC_RELAXED, __HIP_MEMORY_SCOPE_AGENT);
            win = (old == (unsigned)(nsblk - 1));
        }
        win = __shfl(win, 0);
        if (win) {
            __builtin_amdgcn_fence(__ATOMIC_ACQUIRE, "agent");
            float lik = 0.f;
            for (int i = lane; i < CN; i += 64) {
                const float sn = ALD(&Sbuf[2 + C + i]);
                const float sp = ALD(&Sbuf[2 + i / NEG]);
                lik += fmaxf(0.f, 0.5f * (sn - sp) + 1.0f);   // kl_neg - kl_pos + 1
            }
#pragma unroll
            for (int m = 32; m >= 1; m >>= 1) lik += __shfl_xor(lik, m);
            if (lane == 0) {
                const float ld = ALD(&Sbuf[0]);
                const float sx = ALD(&Sbuf[1]);
                out[0] = lik - 0.5f * (sx - (float)KDIM - ld);  // - kl_prior
            }
        }
    }
}

extern "C" void kernel_launch(void* const* d_in, const int* in_sizes, int n_in,
                              void* d_out, int out_size, void* d_ws, size_t ws_size,
                              hipStream_t stream) {
    const int*   x    = (const int*)d_in[0];
    const int*   ctx  = (const int*)d_in[1];
    const int*   negs = (const int*)d_in[2];
    const float* emb  = (const float*)d_in[3];
    const float* Mw   = (const float*)d_in[4];
    const float* Mb   = (const float*)d_in[5];
    const float* Uw   = (const float*)d_in[6];
    const float* Ub   = (const float*)d_in[7];
    const float* Ww   = (const float*)d_in[8];
    const float* Wb   = (const float*)d_in[9];
    const float* pmu  = (const float*)d_in[10];
    const float* psig = (const float*)d_in[11];
    float* ws  = (float*)d_ws;
    float* out = (float*)d_out;

    const int C    = in_sizes[1];          // 50
    const int CN   = in_sizes[2];          // 500
    const int NEG  = CN / C;               // 10
    const int KDIM = in_sizes[5];          // CTX = 1024

    const int ntask = 2 + C + CN;          // 552
    const int nsblk = (ntask + 7) / 8;     // 69 consumer blocks

    k_h<<<CTXDIM / 4, 1024, 0, stream>>>(emb, Mw, Mb, x, ctx, C, ws);
    k_tail<<<256 + nsblk, 512, 0, stream>>>(Uw, Ub, Ww, Wb, pmu, psig,
                                            x, ctx, negs, C, CN, NEG, KDIM,
                                            nsblk, ws, out);
}